// Round 3
// baseline (109.587 us; speedup 1.0000x reference)
//
#include <hip/hip_runtime.h>

#define NN 512
#define MAGIC1 0x4D379A21u
#define MAGIC2 0xB6E58C37u

// ---- grid-resident flag sync (256 blocks x 256 threads; 1 flag per block) ----
// Release: __syncthreads() drains the block's stores to L2 (compiler emits
// s_waitcnt vmcnt(0) before s_barrier), then thread 0 release-stores the magic
// at agent scope (emits L2 writeback on multi-XCD parts). Acquire: each of the
// 256 threads polls one flag with an agent-scope acquire load (L2 invalidate),
// so after __syncthreads() every thread sees every block's prior writes.
__device__ __forceinline__ void flag_signal(unsigned* __restrict__ flags, unsigned magic) {
    __syncthreads();
    if (threadIdx.x == 0)
        __hip_atomic_store(&flags[blockIdx.x], magic,
                           __ATOMIC_RELEASE, __HIP_MEMORY_SCOPE_AGENT);
}
__device__ __forceinline__ void flag_wait_all(unsigned* __restrict__ flags, unsigned magic) {
    while (__hip_atomic_load(&flags[threadIdx.x], magic ? __ATOMIC_ACQUIRE : __ATOMIC_ACQUIRE,
                             __HIP_MEMORY_SCOPE_AGENT) != magic)
        __builtin_amdgcn_s_sleep(2);
    __syncthreads();
}

// ---- single fused kernel: GEMM tile -> grid sync -> rows -> grid sync -> reduce
__global__ __launch_bounds__(256) void sap_one(const float* __restrict__ P,
                                               const int* __restrict__ labels,
                                               float* __restrict__ S,
                                               float* __restrict__ per_anchor,
                                               unsigned* __restrict__ flag1,
                                               unsigned* __restrict__ flag2,
                                               float* __restrict__ out) {
    __shared__ float As[32][33];
    __shared__ float Bs[32][33];
    __shared__ float srow[NN];
    __shared__ float posf[NN];
    __shared__ int   poslist[NN];
    __shared__ int   npos_cnt;
    __shared__ float wave_part[4];
    __shared__ float sh[256];

    const int t = threadIdx.x;
    const int b = blockIdx.x;

    // ================= Phase 1: S = P*P^T, one 32x32 tile per block ==========
    // (verbatim round-0 sap_gemm; b = by*16 + bx)
    {
        const int tx = t & 15, ty = t >> 4;
        const int i0 = (b >> 4) * 32, j0 = (b & 15) * 32;
        float acc00 = 0.f, acc01 = 0.f, acc10 = 0.f, acc11 = 0.f;
        const int lr = t >> 3;        // 0..31
        const int lc = (t & 7) * 4;   // 0,4,...,28

        for (int kt = 0; kt < NN; kt += 32) {
            float4 a  = *(const float4*)&P[(i0 + lr) * NN + kt + lc];
            float4 bb = *(const float4*)&P[(j0 + lr) * NN + kt + lc];
            As[lr][lc + 0] = a.x;  As[lr][lc + 1] = a.y;
            As[lr][lc + 2] = a.z;  As[lr][lc + 3] = a.w;
            Bs[lr][lc + 0] = bb.x; Bs[lr][lc + 1] = bb.y;
            Bs[lr][lc + 2] = bb.z; Bs[lr][lc + 3] = bb.w;
            __syncthreads();
#pragma unroll
            for (int kk = 0; kk < 32; kk++) {
                float a0 = As[2 * ty][kk], a1 = As[2 * ty + 1][kk];
                float b0 = Bs[2 * tx][kk], b1 = Bs[2 * tx + 1][kk];
                acc00 += a0 * b0; acc01 += a0 * b1;
                acc10 += a1 * b0; acc11 += a1 * b1;
            }
            __syncthreads();
        }
        const int i = i0 + 2 * ty, j = j0 + 2 * tx;
        S[i * NN + j]           = acc00;
        S[i * NN + j + 1]       = acc01;
        S[(i + 1) * NN + j]     = acc10;
        S[(i + 1) * NN + j + 1] = acc11;
    }

    // ================= grid sync 1: S fully written ==========================
    flag_signal(flag1, MAGIC1);
    flag_wait_all(flag1, MAGIC1);

    // ================= Phase 2: SmoothAP rows, anchors 2b and 2b+1 ===========
    // (verbatim round-0 sap_rows: 4 waves, idx += 4)
    const int wave = t >> 6, lane = t & 63;
    const float C1   = 100.0f * 1.44269504088896340736f;
    const float CLIP = 50.0f  * 1.44269504088896340736f;

    for (int a = 0; a < 2; ++a) {
        const int i = 2 * b + a;
        __syncthreads();
        if (t == 0) npos_cnt = 0;
        if (t < 4) wave_part[t] = 0.f;
        __syncthreads();
        const int li = labels[i];
        for (int k = t; k < NN; k += 256) {
            srow[k] = S[i * NN + k];
            bool p  = (labels[k] == li) && (k != i);
            posf[k] = p ? 1.f : 0.f;
            if (p) { int idx = atomicAdd(&npos_cnt, 1); poslist[idx] = k; }
        }
        __syncthreads();

        const int cnt = npos_cnt;          // positives excluding self
        if (cnt == 0) {                    // n_pos == 1 -> per_anchor = 0
            if (t == 0) per_anchor[i] = 0.f;
            continue;
        }

        float acc = 0.f;                   // lane-0 accumulation per wave
        for (int idx = wave; idx <= cnt; idx += 4) {   // idx==cnt -> j==i (eye)
            const int   j   = (idx == cnt) ? i : poslist[idx];
            const float sij = srow[j];
            float sum_all = 0.f, sum_pos = 0.f;
#pragma unroll
            for (int kk = 0; kk < 8; kk++) {
                const int k = lane + (kk << 6);
                float y = (sij - srow[k]) * C1;
                y = fminf(fmaxf(y, -CLIP), CLIP);
                float tt = 1.0f / (1.0f + exp2f(y));
                if (k == j) tt = 0.f;      // (1-eye)[j,k] factor
                sum_all += tt;
                sum_pos += tt * posf[k];   // posf[i]==0 excludes k==i
            }
#pragma unroll
            for (int off = 32; off; off >>= 1) {
                sum_all += __shfl_down(sum_all, off);
                sum_pos += __shfl_down(sum_pos, off);
            }
            if (lane == 0) {
                const float den = 1.0f + sum_all;
                acc += ((j == i) ? 1.0f : (1.0f + sum_pos)) / den;
            }
        }
        if (lane == 0) wave_part[wave] = acc;
        __syncthreads();
        if (t == 0) {
            per_anchor[i] = (wave_part[0] + wave_part[1] + wave_part[2] + wave_part[3])
                          / (float)(cnt + 1);
        }
    }

    // ================= grid sync 2 + final reduce in block 0 =================
    flag_signal(flag2, MAGIC2);
    if (b != 0) return;                    // non-zero blocks are done

    flag_wait_all(flag2, MAGIC2);

    // reset flags so the scheme survives replays without a re-poison between
    __hip_atomic_store(&flag1[t], 0u, __ATOMIC_RELAXED, __HIP_MEMORY_SCOPE_AGENT);
    __hip_atomic_store(&flag2[t], 0u, __ATOMIC_RELAXED, __HIP_MEMORY_SCOPE_AGENT);

    // (verbatim round-0 sap_reduce)
    sh[t] = per_anchor[t] + per_anchor[t + 256];
    __syncthreads();
    for (int s = 128; s; s >>= 1) {
        if (t < s) sh[t] += sh[t + s];
        __syncthreads();
    }
    if (t == 0) out[0] = 1.0f - sh[0] / (float)NN;
}

extern "C" void kernel_launch(void* const* d_in, const int* in_sizes, int n_in,
                              void* d_out, int out_size, void* d_ws, size_t ws_size,
                              hipStream_t stream) {
    const float* preds  = (const float*)d_in[0];
    const int*   labels = (const int*)d_in[1];
    float* out = (float*)d_out;

    float*    S          = (float*)d_ws;                    // 512*512 floats = 1 MB
    float*    per_anchor = (float*)d_ws + NN * NN;          // 512 floats
    unsigned* flag1      = (unsigned*)((float*)d_ws + NN * NN + NN);   // 256 u32
    unsigned* flag2      = flag1 + 256;                                // 256 u32

    sap_one<<<NN / 2, 256, 0, stream>>>(preds, labels, S, per_anchor,
                                        flag1, flag2, out);
}

// Round 4
// 71.778 us; speedup vs baseline: 1.5268x; 1.5268x over previous
//
#include <hip/hip_runtime.h>

#define NN 512
#define FMAGIC 0x5AD0F1A6u

// ---------------- single kernel: per-block srow dot + rows + atomic tail reduce
// 256 blocks x 512 threads, 2 anchors per block (i = 2b, 2b+1).
// No cross-block ordinary-memory dependencies: the only grid-wide data flow is
// the final 512-float sum, transmitted through RELAXED agent-scope atomics
// (coherence-point ops; no L2 writeback/invalidate -- the round-3 lesson).
__global__ __launch_bounds__(512) void sap_fused(const float* __restrict__ P,
                                                 const int* __restrict__ labels,
                                                 unsigned* __restrict__ pa_bits,
                                                 unsigned* __restrict__ flags,
                                                 float* __restrict__ out) {
    __shared__ float srow[2][NN];
    __shared__ int   labels_sh[NN];
    __shared__ float posf[NN];
    __shared__ int   poslist[NN];
    __shared__ int   npos_cnt;
    __shared__ float wave_part[8];
    __shared__ float pa_out[2];
    __shared__ float sh[256];

    const int t    = threadIdx.x;          // 0..511
    const int lane = t & 63;
    const int wave = t >> 6;               // 0..7
    const int g    = lane & 15;            // lane within 16-group
    const int grp  = lane >> 4;            // 0..3: row-group within wave
    const int b    = blockIdx.x;
    const int i0   = b * 2;

    if (t < 128) ((int4*)labels_sh)[t] = ((const int4*)labels)[t];

    // ---- anchor rows into registers: lane's slots are float4 indices {g+16c}
    float4 a0[8], a1[8];
    {
        const float4* A0 = (const float4*)&P[i0 * NN];
        const float4* A1 = (const float4*)&P[(i0 + 1) * NN];
#pragma unroll
        for (int c = 0; c < 8; ++c) {
            a0[c] = A0[g + 16 * c];
            a1[c] = A1[g + 16 * c];
        }
    }

    // ---- dot phase (verbatim round-2): wave w owns rows [64w, 64w+64)
#pragma unroll 4
    for (int bb_ = 0; bb_ < 16; ++bb_) {
        const int k = wave * 64 + bb_ * 4 + grp;
        const float4* B = (const float4*)&P[k * NN];
        float s0 = 0.f, s1 = 0.f;
#pragma unroll
        for (int c = 0; c < 8; ++c) {
            const float4 bb = B[g + 16 * c];
            s0 += a0[c].x * bb.x; s0 += a0[c].y * bb.y;
            s0 += a0[c].z * bb.z; s0 += a0[c].w * bb.w;
            s1 += a1[c].x * bb.x; s1 += a1[c].y * bb.y;
            s1 += a1[c].z * bb.z; s1 += a1[c].w * bb.w;
        }
#pragma unroll
        for (int off = 1; off < 16; off <<= 1) {   // stays within the 16-group
            s0 += __shfl_xor(s0, off);
            s1 += __shfl_xor(s1, off);
        }
        if (g == 0) { srow[0][k] = s0; srow[1][k] = s1; }
    }

    // ---- rows phase (verbatim round-2)
    const float C1   = 100.0f * 1.44269504088896340736f;
    const float CLIP = 50.0f  * 1.44269504088896340736f;

    for (int a = 0; a < 2; ++a) {
        const int i = i0 + a;
        __syncthreads();                   // srow ready / protect reused buffers
        if (t == 0) npos_cnt = 0;
        if (t < 8) wave_part[t] = 0.f;
        __syncthreads();
        const int li = labels_sh[i];
        {
            bool p  = (labels_sh[t] == li) && (t != i);
            posf[t] = p ? 1.f : 0.f;
            if (p) { int idx = atomicAdd(&npos_cnt, 1); poslist[idx] = t; }
        }
        __syncthreads();

        const int cnt = npos_cnt;          // positives excluding self
        if (cnt == 0) {                    // n_pos == 1 -> per_anchor = 0
            if (t == 0) pa_out[a] = 0.f;
            continue;
        }

        const float* sr = srow[a];
        float acc = 0.f;                   // lane-0 accumulation per wave
        for (int idx = wave; idx <= cnt; idx += 8) {   // idx==cnt -> j==i (eye)
            const int   j   = (idx == cnt) ? i : poslist[idx];
            const float sij = sr[j];
            float sum_all = 0.f, sum_pos = 0.f;
#pragma unroll
            for (int kk = 0; kk < 8; kk++) {
                const int k = lane + (kk << 6);
                float y = (sij - sr[k]) * C1;
                y = fminf(fmaxf(y, -CLIP), CLIP);
                float tt = 1.0f / (1.0f + exp2f(y));
                if (k == j) tt = 0.f;      // (1-eye)[j,k] factor
                sum_all += tt;
                sum_pos += tt * posf[k];   // posf[i]==0 excludes k==i
            }
#pragma unroll
            for (int off = 32; off; off >>= 1) {
                sum_all += __shfl_down(sum_all, off);
                sum_pos += __shfl_down(sum_pos, off);
            }
            if (lane == 0) {
                const float den = 1.0f + sum_all;
                acc += ((j == i) ? 1.0f : (1.0f + sum_pos)) / den;
            }
        }
        if (lane == 0) wave_part[wave] = acc;
        __syncthreads();
        if (t == 0) {
            float tot = 0.f;
#pragma unroll
            for (int w = 0; w < 8; ++w) tot += wave_part[w];
            pa_out[a] = tot / (float)(cnt + 1);
        }
    }
    __syncthreads();

    // ---- publish this block's two per_anchor values + flag (all relaxed atomics)
    if (t == 0) {
        __hip_atomic_store(&pa_bits[i0],     __float_as_uint(pa_out[0]),
                           __ATOMIC_RELAXED, __HIP_MEMORY_SCOPE_AGENT);
        __hip_atomic_store(&pa_bits[i0 + 1], __float_as_uint(pa_out[1]),
                           __ATOMIC_RELAXED, __HIP_MEMORY_SCOPE_AGENT);
        // order data-atomics before flag-atomic without any cache writeback:
        asm volatile("s_waitcnt vmcnt(0)" ::: "memory");
        __hip_atomic_store(&flags[b], FMAGIC,
                           __ATOMIC_RELAXED, __HIP_MEMORY_SCOPE_AGENT);
    }

    if (b != 0) return;                    // finisher is block 0

    // ---- block 0: wait for all flags (relaxed polls -> no L2 inv storm)
    if (t < 256) {
        while (__hip_atomic_load(&flags[t], __ATOMIC_RELAXED,
                                 __HIP_MEMORY_SCOPE_AGENT) != FMAGIC)
            __builtin_amdgcn_s_sleep(8);
        // reset for replay-robustness (0 != FMAGIC)
        __hip_atomic_store(&flags[t], 0u, __ATOMIC_RELAXED,
                           __HIP_MEMORY_SCOPE_AGENT);
    }
    __syncthreads();

    // ---- final reduce (bitwise-identical round-0 tree)
    if (t < 256) {
        float v0 = __uint_as_float(__hip_atomic_load(&pa_bits[t], __ATOMIC_RELAXED,
                                                     __HIP_MEMORY_SCOPE_AGENT));
        float v1 = __uint_as_float(__hip_atomic_load(&pa_bits[t + 256], __ATOMIC_RELAXED,
                                                     __HIP_MEMORY_SCOPE_AGENT));
        sh[t] = v0 + v1;
    }
    __syncthreads();
    for (int s = 128; s; s >>= 1) {
        if (t < s) sh[t] += sh[t + s];
        __syncthreads();
    }
    if (t == 0) out[0] = 1.0f - sh[0] / (float)NN;
}

extern "C" void kernel_launch(void* const* d_in, const int* in_sizes, int n_in,
                              void* d_out, int out_size, void* d_ws, size_t ws_size,
                              hipStream_t stream) {
    const float* preds  = (const float*)d_in[0];
    const int*   labels = (const int*)d_in[1];
    float* out = (float*)d_out;

    unsigned* pa_bits = (unsigned*)d_ws;           // 512 u32 (float bits)
    unsigned* flags   = pa_bits + NN;              // 256 u32

    sap_fused<<<NN / 2, 512, 0, stream>>>(preds, labels, pa_bits, flags, out);
}